// Round 8
// baseline (143.089 us; speedup 1.0000x reference)
//
#include <hip/hip_runtime.h>
#include <stdint.h>

// Problem constants
#define B_  1024
#define D_  512
#define K_  255
#define L_  256
#define C_  80

typedef __attribute__((ext_vector_type(8))) short bf16x8;
typedef __attribute__((ext_vector_type(4))) float f32x4;
typedef __attribute__((ext_vector_type(8))) short short8;

// async global->LDS, 16B per lane; dst must be wave-uniform base + lane*16.
#define GLD(gsrc, ldst) \
  __builtin_amdgcn_global_load_lds((const __attribute__((address_space(1))) void*)(gsrc), \
                                   (__attribute__((address_space(3))) void*)(ldst), 16, 0, 0)

__device__ __forceinline__ short cvt_bf16(float f) {
    unsigned u = __float_as_uint(f);
    u += 0x7FFFu + ((u >> 16) & 1u);
    return (short)(u >> 16);
}

__device__ __forceinline__ short8 cvt8(float4 a, float4 b) {
    short8 o;
    o[0] = cvt_bf16(a.x); o[1] = cvt_bf16(a.y); o[2] = cvt_bf16(a.z); o[3] = cvt_bf16(a.w);
    o[4] = cvt_bf16(b.x); o[5] = cvt_bf16(b.y); o[6] = cvt_bf16(b.z); o[7] = cvt_bf16(b.w);
    return o;
}

// ---------------------------------------------------------------------------
// Kernel 1: convert x (1024x512) fp32->bf16 and normalize ne rows -> bf16 neb
// (256 rows; row 255 zeroed). W-conversion REMOVED (folded into gemm, which
// had idle VALU + idle HBM). ~2.5 MB traffic -> ~1.3 us.
// Grid 512: blocks 0..255 = x granules, 256..511 = ne rows.
// ---------------------------------------------------------------------------
__global__ __launch_bounds__(256) void convert_kernel(const float* __restrict__ x,
                                                      const float* __restrict__ ne,
                                                      short* __restrict__ xb,
                                                      short* __restrict__ neb) {
    __shared__ float red[256];
    const int tid = threadIdx.x;
    if (blockIdx.x < 256) {
        size_t v = (size_t)blockIdx.x * 256 + tid;   // < 65536
        float4 a = ((const float4*)x)[v * 2];
        float4 b = ((const float4*)x)[v * 2 + 1];
        ((short8*)xb)[v] = cvt8(a, b);
    } else {
        const int row = blockIdx.x - 256;  // 0..255
        if (row == 255) {
            ((unsigned*)(neb + 255 * 512))[tid] = 0u;  // pad row = zeros
            return;
        }
        const float2* nr = (const float2*)(ne + (size_t)row * 512);
        float2 a = nr[tid];
        red[tid] = a.x * a.x + a.y * a.y;
        __syncthreads();
        #pragma unroll
        for (int s = 128; s > 0; s >>= 1) {
            if (tid < s) red[tid] += red[tid + s];
            __syncthreads();
        }
        float inv = rsqrtf(red[0]);
        unsigned lo = (unsigned short)cvt_bf16(a.x * inv);
        unsigned hi = (unsigned short)cvt_bf16(a.y * inv);
        ((unsigned*)(neb + (size_t)row * 512))[tid] = lo | (hi << 16);
    }
}

// ---------------------------------------------------------------------------
// Kernel 2: sim GEMM: out1[b,k] = sigmoid(xb[b,:]·neb[k,:]). 64x64 tiles.
// ---------------------------------------------------------------------------
__global__ __launch_bounds__(256) void simgemm_kernel(const short* __restrict__ xb,
                                                      const short* __restrict__ neb,
                                                      float* __restrict__ out1) {
    __shared__ __align__(16) short Ald[512 * 8];
    __shared__ __align__(16) short Bld[512 * 8];
    const int tid = threadIdx.x;
    const int lane = tid & 63, wave = tid >> 6;
    const int q = lane >> 4, r = lane & 15;
    const int mt = blockIdx.x >> 2;
    const int nt = blockIdx.x & 3;

    f32x4 acc[4];
    #pragma unroll
    for (int nf = 0; nf < 4; ++nf) acc[nf] = (f32x4){0.f, 0.f, 0.f, 0.f};

    const bf16x8* Av = (const bf16x8*)Ald;
    const bf16x8* Bv = (const bf16x8*)Bld;

    for (int kb = 0; kb < 8; ++kb) {
        __syncthreads();
        #pragma unroll
        for (int j = 0; j < 2; ++j) {
            int ph = j * 256 + tid, rr = ph >> 3, g = (ph & 7) ^ (rr & 7);
            GLD(xb + ((size_t)(mt * 64 + rr) * D_ + kb * 64 + g * 8), Ald + ph * 8);
        }
        #pragma unroll
        for (int j = 0; j < 2; ++j) {
            int ph = j * 256 + tid, cc = ph >> 3, g = (ph & 7) ^ (cc & 7);
            GLD(neb + ((size_t)(nt * 64 + cc) * D_ + kb * 64 + g * 8), Bld + ph * 8);
        }
        __syncthreads();
        #pragma unroll
        for (int ks = 0; ks < 2; ++ks) {
            const int g = ks * 4 + q;
            int rl = wave * 16 + r;
            bf16x8 af = Av[rl * 8 + (g ^ (rl & 7))];
            #pragma unroll
            for (int nf = 0; nf < 4; ++nf) {
                int cl = nf * 16 + r;
                bf16x8 bfr = Bv[cl * 8 + (g ^ (cl & 7))];
                acc[nf] = __builtin_amdgcn_mfma_f32_16x16x32_bf16(af, bfr, acc[nf], 0, 0, 0);
            }
        }
    }
    #pragma unroll
    for (int nf = 0; nf < 4; ++nf) {
        int gcol = nt * 64 + nf * 16 + r;
        if (gcol < K_) {
            #pragma unroll
            for (int i = 0; i < 4; ++i) {
                int grow = mt * 64 + wave * 16 + q * 4 + i;
                out1[(size_t)grow * K_ + gcol] = 1.f / (1.f + __expf(-acc[nf][i]));
            }
        }
    }
}

// ---------------------------------------------------------------------------
// Kernel 3: leaf probabilities from out1 sigmoids. Block = batch row.
// Also zeroes out0 (runs before gemm/reduce; reduce atomicAdds into it).
// ---------------------------------------------------------------------------
__global__ __launch_bounds__(256) void leafprob_kernel(const float* __restrict__ out1,
                                                       float* __restrict__ p_ws,
                                                       float* __restrict__ out0) {
    __shared__ float ss[K_];
    const int b = blockIdx.x, t = threadIdx.x;
    if (t < K_) ss[t] = out1[(size_t)b * K_ + t];
    if (t < C_) out0[(size_t)b * C_ + t] = 0.f;   // zero-init for reduce atomics
    __syncthreads();
    float prob = 1.f;
    int node = 0;
    #pragma unroll
    for (int d = 0; d < 8; ++d) {
        int bit = (t >> (7 - d)) & 1;
        float s = ss[node];
        prob *= bit ? (1.f - s) : s;
        node = 2 * node + 1 + bit;
    }
    p_ws[(size_t)b * L_ + t] = prob;
}

// ---------------------------------------------------------------------------
// Kernel 4: main GEMM with FUSED W-CONVERSION (reg-staged B).
// Round-8 theory: 8 structural variants bracket gemm at 30-37 us = the
// documented 2-phase structural ceiling (~700 TF); stop pushing the
// schedule. Instead claim convert's ~10 us: B is now loaded as f32 from lW,
// converted in-register (cvt_bf16, identical numerics to the old convert),
// and ds_written to Bld. gemm has idle VALU (13%) and idle HBM (16%) to
// absorb this. wb and its 83 MB of traffic are gone.
// Schedule detail that makes reg-staging cheap with plain __syncthreads:
// B-loads for stage s+1 are issued AFTER the post-stage barrier, so they
// remain outstanding through the 40-MFMA compute (VGPR-destined loads are
// only drained at fence/use, unlike global_load_lds); the drain at the next
// top-barrier catches only their tail.
// Stage shape = round-0's best-measured: K=128, 1 leaf/stage, 16 stages,
// A via GLD once per kb. LDS: A 32 KB + B 20 KB + p 2 KB = 54 KB -> 2
// blocks/CU at (256,2). bq[10] f32x4 prefetch regs -> VGPR ~160-200
// (budget 256 at 2 waves/SIMD; watch VGPR_Count + WRITE_SIZE for spill).
// Grid = mt(8) x lc(64) = 512; blockIdx%8 = lc%8 keeps the 8 m-tiles
// sharing a W slab on one XCD (f32 W slab L2/L3-resident).
// ---------------------------------------------------------------------------
__global__ __launch_bounds__(256, 2) void gemm_kernel(const short* __restrict__ xb,
                                                      const float* __restrict__ lW,
                                                      const float* __restrict__ p,
                                                      const float* __restrict__ lb,
                                                      float* __restrict__ partial) {
    __shared__ __align__(16) short Ald[2048 * 8];  // 128 rows x 16 granules = 32 KB
    __shared__ __align__(16) short Bld[1280 * 8];  // 80 rows x 16 granules = 20 KB
    __shared__ __align__(16) float p_t[4][128];    // transposed p tile, 2 KB

    const int tid = threadIdx.x;
    const int lane = tid & 63, wave = tid >> 6;
    const int q = lane >> 4, r = lane & 15;
    const int wrow = wave * 32;
    const int lc = blockIdx.x & 63;   // 64 l-chunks of 4 leaves
    const int mt = blockIdx.x >> 6;   // 8 m-tiles of 128 rows

    // B prefetch registers: 5 granules/thread x (2 float4 each) = 40 VGPR
    float4 bq[10];
    auto loadB = [&](int l, int kb) {
        #pragma unroll
        for (int j = 0; j < 5; ++j) {
            int ph = j * 256 + tid;
            int cc = ph >> 4;
            int g  = (ph & 15) ^ (cc & 15);
            const float4* s = (const float4*)(lW + ((size_t)(l * C_ + cc)) * D_ + kb * 128 + g * 8);
            bq[2 * j]     = s[0];
            bq[2 * j + 1] = s[1];
        }
    };
    auto writeB = [&]() {   // cvt + ds_write to the same swizzled layout GLD used
        #pragma unroll
        for (int j = 0; j < 5; ++j) {
            int ph = j * 256 + tid;
            ((short8*)Bld)[ph] = cvt8(bq[2 * j], bq[2 * j + 1]);
        }
    };

    // prologue: issue B(0) first so its latency hides under p_t/init work
    loadB(lc * 4 + 0, 0);

    if (tid < 128) {
        float4 pw = *(const float4*)(p + (size_t)(mt * 128 + tid) * L_ + lc * 4);
        p_t[0][tid] = pw.x; p_t[1][tid] = pw.y;
        p_t[2][tid] = pw.z; p_t[3][tid] = pw.w;
    }
    __syncthreads();  // p_t visible (drains bq(0) too — one-time cost)

    // outacc init = bias term: sum_li p_t[li][row] * lb[(lc*4+li)*80 + col]
    f32x4 outacc[2][5];
    #pragma unroll
    for (int mf = 0; mf < 2; ++mf) {
        const int base = wrow + mf * 16 + q * 4;
        f32x4 pf[4];
        #pragma unroll
        for (int li = 0; li < 4; ++li) pf[li] = *(const f32x4*)&p_t[li][base];
        #pragma unroll
        for (int nf = 0; nf < 5; ++nf) {
            f32x4 s = pf[0] * lb[(size_t)(lc * 4 + 0) * C_ + nf * 16 + r];
            s += pf[1] * lb[(size_t)(lc * 4 + 1) * C_ + nf * 16 + r];
            s += pf[2] * lb[(size_t)(lc * 4 + 2) * C_ + nf * 16 + r];
            s += pf[3] * lb[(size_t)(lc * 4 + 3) * C_ + nf * 16 + r];
            outacc[mf][nf] = s;
        }
    }

    const bf16x8* Av = (const bf16x8*)Ald;
    const bf16x8* Bv = (const bf16x8*)Bld;
    const f32x4 z4 = {0.f, 0.f, 0.f, 0.f};

    for (int kb = 0; kb < 4; ++kb) {      // 4 K=128 chunks, A staged once each
        for (int li = 0; li < 4; ++li) {  // 1 leaf per stage -> 16 stages
            __syncthreads();  // prev stage's readers done; drains bq tail (landed during compute)
            writeB();         // B(s): cvt + ds_write (compiler waits bq at use)
            if (li == 0) {
                // stage A: 2048 granules (128 rows x 16), 8 per thread, via GLD
                #pragma unroll
                for (int j = 0; j < 8; ++j) {
                    int ph = j * 256 + tid;
                    int rr = ph >> 4;
                    int g  = (ph & 15) ^ (rr & 15);
                    GLD(xb + ((size_t)(mt * 128 + rr) * D_ + kb * 128 + g * 8), Ald + ph * 8);
                }
            }
            __syncthreads();  // drains A-GLD vmcnt + ds_write lgkm: tiles ready

            // issue NEXT stage's B loads now — they stay outstanding (VGPR
            // dest) through the 40 MFMAs below and land before next barrier
            {
                int nkb = kb, nli = li + 1;
                if (nli == 4) { nli = 0; ++nkb; }
                if (nkb < 4) loadB(lc * 4 + nli, nkb);
            }

            f32x4 dec[2][5];
            #pragma unroll
            for (int ks = 0; ks < 4; ++ks) {  // 4 K=32 slices -> 40 MFMA/stage
                const int g = ks * 4 + q;
                bf16x8 af[2], bfr[5];
                #pragma unroll
                for (int mf = 0; mf < 2; ++mf) {
                    int rl = wrow + mf * 16 + r;
                    af[mf] = Av[rl * 16 + (g ^ (rl & 15))];
                }
                #pragma unroll
                for (int nf = 0; nf < 5; ++nf) {
                    int cl = nf * 16 + r;
                    bfr[nf] = Bv[cl * 16 + (g ^ (cl & 15))];
                }
                #pragma unroll
                for (int mf = 0; mf < 2; ++mf)
                    #pragma unroll
                    for (int nf = 0; nf < 5; ++nf)
                        dec[mf][nf] = __builtin_amdgcn_mfma_f32_16x16x32_bf16(
                            af[mf], bfr[nf], ks == 0 ? z4 : dec[mf][nf], 0, 0, 0);
            }

            // packed linear p-fold of this (kb,li) chunk
            #pragma unroll
            for (int mf = 0; mf < 2; ++mf) {
                f32x4 pf4 = *(const f32x4*)&p_t[li][wrow + mf * 16 + q * 4];
                #pragma unroll
                for (int nf = 0; nf < 5; ++nf)
                    outacc[mf][nf] += pf4 * dec[mf][nf];
            }
        }
    }

    // store partials: partial[lc][1024 rows][80 cols], this block owns 128 rows
    const size_t rbase = (size_t)lc * B_ + mt * 128;
    #pragma unroll
    for (int mf = 0; mf < 2; ++mf)
        #pragma unroll
        for (int nf = 0; nf < 5; ++nf)
            #pragma unroll
            for (int i = 0; i < 4; ++i) {
                int row = wrow + mf * 16 + q * 4 + i;
                int col = nf * 16 + r;
                partial[(rbase + row) * C_ + col] = outacc[mf][nf][i];
            }
}

// ---------------------------------------------------------------------------
// Kernel 5: reduce 64 lc partials -> out0 (1024x80).
// Grid 640 = 80 idx-chunks x 8 j-groups: each thread sums 8 slabs and
// atomicAdds (8-way contention only; out0 zeroed by leafprob).
// ---------------------------------------------------------------------------
__global__ __launch_bounds__(256) void reduce_kernel(const float* __restrict__ partial,
                                                     float* __restrict__ out0) {
    const int chunk = blockIdx.x >> 3;            // 0..79
    const int jg    = blockIdx.x & 7;             // 0..7
    const int idx   = chunk * 256 + threadIdx.x;  // float4 index < 20480
    const float4* p4 = (const float4*)partial;
    float4 s = {0.f, 0.f, 0.f, 0.f};
    #pragma unroll
    for (int j = 0; j < 8; ++j) {
        float4 v = p4[(size_t)(jg * 8 + j) * (B_ * C_ / 4) + idx];
        s.x += v.x; s.y += v.y; s.z += v.z; s.w += v.w;
    }
    float* o = out0 + (size_t)idx * 4;
    atomicAdd(o + 0, s.x);
    atomicAdd(o + 1, s.y);
    atomicAdd(o + 2, s.z);
    atomicAdd(o + 3, s.w);
}

// ---------------------------------------------------------------------------
extern "C" void kernel_launch(void* const* d_in, const int* in_sizes, int n_in,
                              void* d_out, int out_size, void* d_ws, size_t ws_size,
                              hipStream_t stream) {
    const float* x  = (const float*)d_in[0];  // 1024x512
    const float* ne = (const float*)d_in[1];  // 255x512
    const float* lW = (const float*)d_in[2];  // 20480x512 (read f32 by gemm)
    const float* lb = (const float*)d_in[3];  // 20480
    // d_in[4] res_path: deterministic structure, traversed directly

    float* out0 = (float*)d_out;            // 1024x80
    float* out1 = out0 + (size_t)B_ * C_;   // 1024x255

    char* ws = (char*)d_ws;
    short* xb      = (short*)ws;                             // 1 MB
    short* neb     = (short*)(ws + (1u << 20));              // 256 KB
    float* p_ws    = (float*)(ws + (1u << 20) + (1u << 18)); // 1 MB
    float* partial = (float*)(ws + (24u << 20));             // 21 MB (64x1024x80)

    convert_kernel<<<512, 256, 0, stream>>>(x, ne, xb, neb);
    simgemm_kernel<<<64, 256, 0, stream>>>(xb, neb, out1);
    leafprob_kernel<<<B_, 256, 0, stream>>>(out1, p_ws, out0);
    gemm_kernel<<<512, 256, 0, stream>>>(xb, lW, p_ws, lb, partial);
    reduce_kernel<<<640, 256, 0, stream>>>(partial, out0);
}